// Round 1
// baseline (197.551 us; speedup 1.0000x reference)
//
#include <hip/hip_runtime.h>
#include <stdint.h>

#define NS 65536      // B*H*W samples
#define D 64          // embed dim
#define K 1024        // codebook size
#define NEL 4194304   // NS*D
#define MARGIN 0.05f  // approx-dist uncertainty margin (>> 2*eps ~ 1.4e-3)

typedef short bf16x8 __attribute__((ext_vector_type(8)));
typedef short s16x4 __attribute__((ext_vector_type(4)));
typedef float f32x4 __attribute__((ext_vector_type(4)));

static __device__ __forceinline__ unsigned short bf16_rne(float x) {
    union { float f; uint32_t u; } v; v.f = x;
    uint32_t r = v.u + 0x7FFFu + ((v.u >> 16) & 1u);
    return (unsigned short)(r >> 16);
}
static __device__ __forceinline__ float bf16f(unsigned short h) {
    union { uint32_t u; float f; } v; v.u = ((uint32_t)h) << 16;
    return v.f;
}

// ---------------------------------------------------------------------------
// Prep: split codebook into bf16 hi/lo [K][D] row-major (MFMA-B-ready),
// compute ||m_k||^2 in fp32, zero the loss accumulator.
// 64 blocks (vs 16 before): 4 loads/thread -> latency-bound time /4.
// ---------------------------------------------------------------------------
__global__ __launch_bounds__(256) void vq_prep(
    const float* __restrict__ cm,        // [D,K]
    unsigned short* __restrict__ mhi,    // [K,D] bf16 bits
    unsigned short* __restrict__ mlo,    // [K,D] bf16 bits
    float* __restrict__ cnorm,           // [K]
    double* __restrict__ acc)
{
    const int tx = threadIdx.x;
    const int kl = tx & 15;              // code within block's 16
    const int dg = tx >> 4;              // dim group 0..15 (4 dims each)
    const int k = blockIdx.x * 16 + kl;
    if (blockIdx.x == 0 && tx == 0) *acc = 0.0;

    float p = 0.f;
    s16x4 hv, lv;
#pragma unroll
    for (int j = 0; j < 4; ++j) {
        float v = cm[(dg * 4 + j) * K + k];   // 16 consecutive floats / 16 lanes
        unsigned short hb = bf16_rne(v);
        hv[j] = (short)hb;
        lv[j] = (short)bf16_rne(v - bf16f(hb));
        p = fmaf(v, v, p);
    }
    *(s16x4*)(mhi + (size_t)k * D + dg * 4) = hv;
    *(s16x4*)(mlo + (size_t)k * D + dg * 4) = lv;

    __shared__ float pn[16][17];
    pn[kl][dg] = p;
    __syncthreads();
    if (tx < 16) {
        float s = 0.f;
#pragma unroll
        for (int g = 0; g < 16; ++g) s += pn[tx][g];
        cnorm[blockIdx.x * 16 + tx] = s;
    }
}

// ---------------------------------------------------------------------------
// Main: barrier-free MFMA distance loop.
// 1024 blocks x 256 thr (4 waves). Wave w handles samples w*16..+16 vs ALL
// 1024 codes in 64 tiles of 16. B fragments (mhi/mlo, 256 KB total = L2/L1
// resident) are loaded DIRECTLY global->VGPR per tile (4x dwordx4/lane,
// register double-buffered one tile ahead) -- no LDS staging, hence ZERO
// __syncthreads() in the main loop (previous version: 128/block, each
// draining vmcnt(0); that was the 72us -> ~13us-floor gap).
// dot = x_hi.m_hi + x_hi.m_lo + x_lo.m_hi accumulated in ONE chained MFMA
// accumulator (saves 2 VALU adds/elem); top-2 via v_min/v_med3 + exact
// index cndmasks (8 VALU/elem). Margin cases rescored exactly in fp32.
// Merge-phase LDS arrays are skewed +4*(tx>>4): the old layout's read
// pattern was a 16-way bank conflict (the 983k SQ_LDS_BANK_CONFLICT).
// ---------------------------------------------------------------------------
__global__ __launch_bounds__(256, 4) void vq_main(
    const float* __restrict__ xin,           // [NS,D]
    const float* __restrict__ cm,            // [D,K] (exact rescore)
    const unsigned short* __restrict__ mhi,  // [K,D]
    const unsigned short* __restrict__ mlo,  // [K,D]
    const float* __restrict__ cnorm,         // [K]
    float* __restrict__ outq,                // [NS,D]
    float* __restrict__ outidx,              // [NS]
    double* __restrict__ acc_g)
{
    // smemA phase1: xh[64][72] + xl[64][72] (18432 B)
    // smemA phase2 (alias): skewed mb1/mb2 f32[1088] + mi1/mi2 i32[1088]
    // smemA phase3 (alias): red f32[256]
    __shared__ char smemA[18432];
    __shared__ float cn_lds[1024];
    __shared__ int   widx[64];

    unsigned short* xh = (unsigned short*)smemA;           // stride 72
    unsigned short* xl = (unsigned short*)(smemA + 9216);
    float* mb1 = (float*)smemA;                  // 1088 floats (skewed)
    float* mb2 = (float*)(smemA + 4352);
    int*   mi1 = (int*)(smemA + 8704);
    int*   mi2 = (int*)(smemA + 13056);
    float* red = (float*)smemA;

    const int tx = threadIdx.x;
    const int S0 = blockIdx.x * 64;
    const int w = tx >> 6, l = tx & 63;
    const int quad = l >> 4, col = l & 15;

    // B fragment pointers: lane l needs m[t*16 + col][quad*8 .. +8] (16 B)
    // and +32 dims (offset 64 B). Advance 16*D shorts (2 KB) per tile.
    const unsigned short* ph = mhi + (size_t)col * D + quad * 8;
    const unsigned short* pl = mlo + (size_t)col * D + quad * 8;
    bf16x8 nh0 = *(const bf16x8*)(ph);
    bf16x8 nh1 = *(const bf16x8*)(ph + 32);
    bf16x8 nl0 = *(const bf16x8*)(pl);
    bf16x8 nl1 = *(const bf16x8*)(pl + 32);

    // ---- stage x -> bf16 hi/lo in LDS (one-time, one barrier) ----
    {
        const int s = tx >> 2, d0 = (tx & 3) * 16;
        const float* gp = xin + (size_t)(S0 + s) * D + d0;
        bf16x8 hv0, hv1, lv0, lv1;
#pragma unroll
        for (int j = 0; j < 8; ++j) {
            float va = gp[j], vb = gp[8 + j];
            unsigned short ha = bf16_rne(va), hb = bf16_rne(vb);
            hv0[j] = (short)ha; hv1[j] = (short)hb;
            lv0[j] = (short)bf16_rne(va - bf16f(ha));
            lv1[j] = (short)bf16_rne(vb - bf16f(hb));
        }
        *(bf16x8*)(xh + s * 72 + d0)     = hv0;
        *(bf16x8*)(xh + s * 72 + d0 + 8) = hv1;
        *(bf16x8*)(xl + s * 72 + d0)     = lv0;
        *(bf16x8*)(xl + s * 72 + d0 + 8) = lv1;
#pragma unroll
        for (int q = 0; q < 4; ++q) cn_lds[q * 256 + tx] = cnorm[q * 256 + tx];
    }
    __syncthreads();

    // loop-invariant A fragments: sample = w*16 + col, dims quad*8 (+32)
    const int srow = w * 16 + col;
    bf16x8 ahi0 = *(const bf16x8*)(xh + srow * 72 + quad * 8);
    bf16x8 ahi1 = *(const bf16x8*)(xh + srow * 72 + 32 + quad * 8);
    bf16x8 alo0 = *(const bf16x8*)(xl + srow * 72 + quad * 8);
    bf16x8 alo1 = *(const bf16x8*)(xl + srow * 72 + 32 + quad * 8);

    float b1[4], b2[4]; int i1[4], i2[4];
#pragma unroll
    for (int r = 0; r < 4; ++r) { b1[r] = 3.4e38f; b2[r] = 3.4e38f; i1[r] = 0; i2[r] = 0; }

#pragma unroll 2
    for (int t = 0; t < 64; ++t) {
        bf16x8 bh0 = nh0, bh1 = nh1, bl0 = nl0, bl1 = nl1;
        ph += 16 * D; pl += 16 * D;
        if (t < 63) {                    // prefetch tile t+1 into regs
            nh0 = *(const bf16x8*)(ph);
            nh1 = *(const bf16x8*)(ph + 32);
            nl0 = *(const bf16x8*)(pl);
            nl1 = *(const bf16x8*)(pl + 32);
        }
        const int kcode = t * 16 + col;
        const float cn = cn_lds[kcode];
        f32x4 acc = {0.f, 0.f, 0.f, 0.f};   // single chained accumulator
        acc = __builtin_amdgcn_mfma_f32_16x16x32_bf16(ahi0, bh0, acc, 0, 0, 0);
        acc = __builtin_amdgcn_mfma_f32_16x16x32_bf16(ahi1, bh1, acc, 0, 0, 0);
        acc = __builtin_amdgcn_mfma_f32_16x16x32_bf16(ahi0, bl0, acc, 0, 0, 0);
        acc = __builtin_amdgcn_mfma_f32_16x16x32_bf16(ahi1, bl1, acc, 0, 0, 0);
        acc = __builtin_amdgcn_mfma_f32_16x16x32_bf16(alo0, bh0, acc, 0, 0, 0);
        acc = __builtin_amdgcn_mfma_f32_16x16x32_bf16(alo1, bh1, acc, 0, 0, 0);
#pragma unroll
        for (int r = 0; r < 4; ++r) {
            float dv = fmaf(-2.f, acc[r], cn);
            bool c1 = dv < b1[r];
            bool c2 = dv < b2[r];
            // med3(old_b1, dv, old_b2) == new second-best; min == new best
            b2[r] = __builtin_amdgcn_fmed3f(b1[r], dv, b2[r]);
            b1[r] = fminf(b1[r], dv);
            i2[r] = c1 ? i1[r] : (c2 ? kcode : i2[r]);
            i1[r] = c1 ? kcode : i1[r];
        }
    }

    // ---- merge per-lane top-2 across the 16 lanes per (wave,quad,reg) ----
    // skew +4*(tx>>4): reader banks become (4c + 16*mw + 4*mq + mr)%32
    // -> 2-way (free) instead of 16-way.
    const int sk = 4 * (tx + (tx >> 4));
#pragma unroll
    for (int r = 0; r < 4; ++r) {
        mb1[sk + r] = b1[r];
        mb2[sk + r] = b2[r];
        mi1[sk + r] = i1[r];
        mi2[sk + r] = i2[r];
    }
    __syncthreads();

    if (tx < 64) {   // thread tx owns local sample tx
        const int mw = tx >> 4, mq = (tx >> 2) & 3, mr = tx & 3;
        float B1 = 3.4e38f, B2 = 3.4e38f; int I1 = 0, I2 = 0;
#pragma unroll
        for (int c = 0; c < 16; ++c) {
            const int tw = mw * 64 + mq * 16 + c;
            const int e = 4 * (tw + (tw >> 4)) + mr;
            float v1 = mb1[e]; int j1 = mi1[e];
            float v2 = mb2[e]; int j2 = mi2[e];
            if (v1 < B1)      { B2 = B1; I2 = I1; B1 = v1; I1 = j1; }
            else if (v1 < B2) { B2 = v1; I2 = j1; }
            if (v2 < B1)      { B2 = B1; I2 = I1; B1 = v2; I1 = j2; }
            else if (v2 < B2) { B2 = v2; I2 = j2; }
        }
        int winner = I1;
        if (B2 - B1 < MARGIN) {
            // exact fp32 rescore of both candidates from original cm
            const float* xp = xin + (size_t)(S0 + tx) * D;
            float a0 = 0, a1 = 0, a2 = 0, a3 = 0, e0 = 0, e1 = 0, e2 = 0, e3 = 0;
            for (int dd = 0; dd < D; dd += 4) {
                float x0 = xp[dd], x1 = xp[dd + 1], x2 = xp[dd + 2], x3 = xp[dd + 3];
                a0 = fmaf(x0, cm[(dd + 0) * K + I1], a0);
                a1 = fmaf(x1, cm[(dd + 1) * K + I1], a1);
                a2 = fmaf(x2, cm[(dd + 2) * K + I1], a2);
                a3 = fmaf(x3, cm[(dd + 3) * K + I1], a3);
                e0 = fmaf(x0, cm[(dd + 0) * K + I2], e0);
                e1 = fmaf(x1, cm[(dd + 1) * K + I2], e1);
                e2 = fmaf(x2, cm[(dd + 2) * K + I2], e2);
                e3 = fmaf(x3, cm[(dd + 3) * K + I2], e3);
            }
            float d1 = fmaf(-2.f, (a0 + a1) + (a2 + a3), cn_lds[I1]);
            float d2 = fmaf(-2.f, (e0 + e1) + (e2 + e3), cn_lds[I2]);
            if (d2 < d1 || (d2 == d1 && I2 < I1)) winner = I2;
        }
        widx[tx] = winner;
    }
    __syncthreads();

    // ---- gather (hi+lo reconstruct, coalesced) + STE + loss partial ----
    const int sl = tx >> 2, d0 = (tx & 3) * 16;
    const int gs = S0 + sl;
    const int wi = widx[sl];
    const unsigned short* mh = mhi + (size_t)wi * D + d0;
    const unsigned short* ml = mlo + (size_t)wi * D + d0;
    bf16x8 h0 = *(const bf16x8*)(mh);
    bf16x8 h1 = *(const bf16x8*)(mh + 8);
    bf16x8 l0 = *(const bf16x8*)(ml);
    bf16x8 l1 = *(const bf16x8*)(ml + 8);
    const float* xr = xin + (size_t)gs * D + d0;
    float* oq = outq + (size_t)gs * D + d0;
    float psum = 0.f;
#pragma unroll
    for (int g = 0; g < 4; ++g) {
        float4 xv = *(const float4*)(xr + 4 * g);
        float q0 = bf16f((unsigned short)(g < 2 ? h0[4 * g + 0] : h1[4 * g - 8 + 0])) +
                   bf16f((unsigned short)(g < 2 ? l0[4 * g + 0] : l1[4 * g - 8 + 0]));
        float q1 = bf16f((unsigned short)(g < 2 ? h0[4 * g + 1] : h1[4 * g - 8 + 1])) +
                   bf16f((unsigned short)(g < 2 ? l0[4 * g + 1] : l1[4 * g - 8 + 1]));
        float q2 = bf16f((unsigned short)(g < 2 ? h0[4 * g + 2] : h1[4 * g - 8 + 2])) +
                   bf16f((unsigned short)(g < 2 ? l0[4 * g + 2] : l1[4 * g - 8 + 2]));
        float q3 = bf16f((unsigned short)(g < 2 ? h0[4 * g + 3] : h1[4 * g - 8 + 3])) +
                   bf16f((unsigned short)(g < 2 ? l0[4 * g + 3] : l1[4 * g - 8 + 3]));
        float dx = q0 - xv.x, dy = q1 - xv.y, dz = q2 - xv.z, dw = q3 - xv.w;
        float4 o;
        o.x = xv.x + dx; o.y = xv.y + dy; o.z = xv.z + dz; o.w = xv.w + dw;
        *(float4*)(oq + 4 * g) = o;
        psum = fmaf(dx, dx, psum);
        psum = fmaf(dy, dy, psum);
        psum = fmaf(dz, dz, psum);
        psum = fmaf(dw, dw, psum);
    }

    if (tx < 64)
        outidx[S0 + tx] = (float)widx[tx];

    red[tx] = psum;
    __syncthreads();
    for (int st = 128; st > 0; st >>= 1) {
        if (tx < st) red[tx] += red[tx + st];
        __syncthreads();
    }
    if (tx == 0) atomicAdd(acc_g, (double)red[0]);
}

// ---------------------------------------------------------------------------
// Finalize: loss = m + 0.25*m where m = mean((q-x)^2)
// ---------------------------------------------------------------------------
__global__ void vq_finalize(const double* __restrict__ acc,
                            float* __restrict__ loss_out)
{
    float m = (float)(*acc / (double)NEL);
    *loss_out = m + 0.25f * m;
}

extern "C" void kernel_launch(void* const* d_in, const int* in_sizes, int n_in,
                              void* d_out, int out_size, void* d_ws, size_t ws_size,
                              hipStream_t stream) {
    const float* xin = (const float*)d_in[0];   // [16,64,64,64] fp32
    const float* cm  = (const float*)d_in[1];   // [64,1024] fp32

    float* out     = (float*)d_out;
    float* outq    = out;                 // 4194304 floats
    float* outidx  = out + NEL;           // 65536 floats (indices)
    float* outloss = out + NEL + NS;      // 1 float

    // workspace: mhi 128 KB | mlo 128 KB | cnorm 4 KB | acc 8 B
    unsigned short* mhi = (unsigned short*)d_ws;
    unsigned short* mlo = mhi + (size_t)K * D;
    float*  cnorm = (float*)((char*)d_ws + 262144);
    double* acc   = (double*)((char*)d_ws + 266240);

    vq_prep<<<64, 256, 0, stream>>>(cm, mhi, mlo, cnorm, acc);
    vq_main<<<1024, 256, 0, stream>>>(xin, cm, mhi, mlo, cnorm, outq, outidx, acc);
    vq_finalize<<<1, 1, 0, stream>>>(acc, outloss);
}

// Round 2
// 117.974 us; speedup vs baseline: 1.6745x; 1.6745x over previous
//
#include <hip/hip_runtime.h>
#include <stdint.h>

#define NS 65536      // B*H*W samples
#define D 64          // embed dim
#define K 1024        // codebook size
#define NEL 4194304   // NS*D
#define MARGIN 0.05f  // approx-dist uncertainty margin (>> 2*eps ~ 1.4e-3)

typedef short bf16x8 __attribute__((ext_vector_type(8)));
typedef short s16x4 __attribute__((ext_vector_type(4)));
typedef float f32x4 __attribute__((ext_vector_type(4)));

static __device__ __forceinline__ unsigned short bf16_rne(float x) {
    union { float f; uint32_t u; } v; v.f = x;
    uint32_t r = v.u + 0x7FFFu + ((v.u >> 16) & 1u);
    return (unsigned short)(r >> 16);
}
static __device__ __forceinline__ float bf16f(unsigned short h) {
    union { uint32_t u; float f; } v; v.u = ((uint32_t)h) << 16;
    return v.f;
}

// ---------------------------------------------------------------------------
// Prep: split codebook into bf16 hi/lo and pack in MFMA-FRAGMENT order:
//   P[tile t][frag f][lane l][8 shorts],  t=k>>4, f: 0=hi d0-31, 1=hi d32-63,
//   2=lo d0-31, 3=lo d32-63; lane = ((d&31)>>3)*16 + (k&15), elem = d&7.
// So vq_main's per-tile B loads are 64-lane CONTIGUOUS 1 KB reads (1 TA
// transaction) instead of 16-line divergent reads (the round-1 regression:
// 128 B row stride made every load 16 L1 transactions).
// Also computes ||m_k||^2 fp32 and zeroes the loss accumulator.
// ---------------------------------------------------------------------------
__global__ __launch_bounds__(256) void vq_prep(
    const float* __restrict__ cm,        // [D,K]
    unsigned short* __restrict__ P,      // packed frags, 256 KB
    float* __restrict__ cnorm,           // [K]
    double* __restrict__ acc)
{
    const int tx = threadIdx.x;
    const int col = tx & 15;             // code within block's 16
    const int dg = tx >> 4;              // dim group 0..15 (4 dims each)
    const int b = blockIdx.x;            // == tile index t
    const int k = b * 16 + col;
    if (b == 0 && tx == 0) *acc = 0.0;

    float p = 0.f;
    s16x4 hv, lv;
#pragma unroll
    for (int j = 0; j < 4; ++j) {
        float v = cm[(dg * 4 + j) * K + k];   // 16 consecutive floats / 16 lanes
        unsigned short hb = bf16_rne(v);
        hv[j] = (short)hb;
        lv[j] = (short)bf16_rne(v - bf16f(hb));
        p = fmaf(v, v, p);
    }
    // dims dg*4..+4 live in frag (dg>>3), lane ((dg>>1)&3)*16+col, elem (dg&1)*4
    const int lane = ((dg >> 1) & 3) * 16 + col;
    const int e0 = (dg & 1) * 4;
    unsigned short* ph = P + ((size_t)(b * 4 + (dg >> 3)) * 64 + lane) * 8 + e0;
    unsigned short* pl = P + ((size_t)(b * 4 + 2 + (dg >> 3)) * 64 + lane) * 8 + e0;
    *(s16x4*)ph = hv;
    *(s16x4*)pl = lv;

    __shared__ float pn[16][17];
    pn[col][dg] = p;
    __syncthreads();
    if (tx < 16) {
        float s = 0.f;
#pragma unroll
        for (int g = 0; g < 16; ++g) s += pn[tx][g];
        cnorm[b * 16 + tx] = s;
    }
}

// ---------------------------------------------------------------------------
// Main: barrier-free MFMA distance loop, fragment-packed B, depth-2 register
// double-buffer (named sets c*/n*, static indexing only -> no scratch).
// 1024 blocks x 256 thr (4 waves). Wave w: samples w*16..+16 vs all 1024
// codes in 64 tiles of 16. Per tile: 4 coalesced 1 KB B loads, 6 chained
// MFMAs with C-in = -||m||^2/2 (distance = -2*acc, so we track the MAX of
// acc -- saves the per-element fma), med3/max top-2, exact-index cndmasks.
// Margin cases rescored exactly in fp32 from original cm.
// ---------------------------------------------------------------------------
__global__ __launch_bounds__(256, 4) void vq_main(
    const float* __restrict__ xin,           // [NS,D]
    const float* __restrict__ cm,            // [D,K] (exact rescore)
    const unsigned short* __restrict__ P,    // packed frags
    const float* __restrict__ cnorm,         // [K]
    float* __restrict__ outq,                // [NS,D]
    float* __restrict__ outidx,              // [NS]
    double* __restrict__ acc_g)
{
    // smemA phase1: xh[64][72] + xl[64][72] (18432 B)
    // smemA phase2 (alias): skewed mb1/mb2 f32[1088] + mi1/mi2 i32[1088]
    // smemA phase3 (alias): red f32[256]
    __shared__ char smemA[18432];
    __shared__ float cn_lds[1024];
    __shared__ int   widx[64];

    unsigned short* xh = (unsigned short*)smemA;           // stride 72
    unsigned short* xl = (unsigned short*)(smemA + 9216);
    float* mb1 = (float*)smemA;                  // 1088 floats (skewed)
    float* mb2 = (float*)(smemA + 4352);
    int*   mi1 = (int*)(smemA + 8704);
    int*   mi2 = (int*)(smemA + 13056);
    float* red = (float*)smemA;

    const int tx = threadIdx.x;
    const int S0 = blockIdx.x * 64;
    const int w = tx >> 6, l = tx & 63;
    const int quad = l >> 4, col = l & 15;

    // B fragment base: tile t, frag f, lane l at P + (t*4+f)*512 + l*8 shorts
    const unsigned short* pb = P + (size_t)l * 8;

#define LDB(B0, B1, B2, B3, T) do {                                   \
        const unsigned short* q_ = pb + (size_t)(T) * 2048;           \
        B0 = *(const bf16x8*)(q_);                                    \
        B1 = *(const bf16x8*)(q_ + 512);                              \
        B2 = *(const bf16x8*)(q_ + 1024);                             \
        B3 = *(const bf16x8*)(q_ + 1536);                             \
    } while (0)

    // issue tile 0/1 B loads immediately (overlap with x staging below)
    bf16x8 c0, c1, c2, c3, n0, n1, n2, n3;
    LDB(c0, c1, c2, c3, 0);
    LDB(n0, n1, n2, n3, 1);

    // ---- stage x -> bf16 hi/lo in LDS (one-time, one barrier) ----
    {
        const int s = tx >> 2, d0 = (tx & 3) * 16;
        const float* gp = xin + (size_t)(S0 + s) * D + d0;
        bf16x8 hv0, hv1, lv0, lv1;
#pragma unroll
        for (int j = 0; j < 8; ++j) {
            float va = gp[j], vb = gp[8 + j];
            unsigned short ha = bf16_rne(va), hb = bf16_rne(vb);
            hv0[j] = (short)ha; hv1[j] = (short)hb;
            lv0[j] = (short)bf16_rne(va - bf16f(ha));
            lv1[j] = (short)bf16_rne(vb - bf16f(hb));
        }
        *(bf16x8*)(xh + s * 72 + d0)     = hv0;
        *(bf16x8*)(xh + s * 72 + d0 + 8) = hv1;
        *(bf16x8*)(xl + s * 72 + d0)     = lv0;
        *(bf16x8*)(xl + s * 72 + d0 + 8) = lv1;
#pragma unroll
        for (int q = 0; q < 4; ++q) cn_lds[q * 256 + tx] = cnorm[q * 256 + tx];
    }
    __syncthreads();

    // loop-invariant A fragments: sample = w*16 + col, dims quad*8 (+32)
    const int srow = w * 16 + col;
    bf16x8 ahi0 = *(const bf16x8*)(xh + srow * 72 + quad * 8);
    bf16x8 ahi1 = *(const bf16x8*)(xh + srow * 72 + 32 + quad * 8);
    bf16x8 alo0 = *(const bf16x8*)(xl + srow * 72 + quad * 8);
    bf16x8 alo1 = *(const bf16x8*)(xl + srow * 72 + 32 + quad * 8);

    // track MAX of acc' = dot - cn/2  (dist = -2*acc', so max acc' = min dist)
    float b1[4], b2[4]; int i1[4], i2[4];
#pragma unroll
    for (int r = 0; r < 4; ++r) { b1[r] = -3.4e38f; b2[r] = -3.4e38f; i1[r] = 0; i2[r] = 0; }

#define COMPUTE(B0, B1, B2, B3, T) do {                                        \
        const int kc_ = (T) * 16 + col;                                        \
        const float h_ = 0.5f * cn_lds[kc_];                                   \
        f32x4 a_ = {-h_, -h_, -h_, -h_};                                       \
        a_ = __builtin_amdgcn_mfma_f32_16x16x32_bf16(ahi0, B0, a_, 0, 0, 0);   \
        a_ = __builtin_amdgcn_mfma_f32_16x16x32_bf16(ahi1, B1, a_, 0, 0, 0);   \
        a_ = __builtin_amdgcn_mfma_f32_16x16x32_bf16(ahi0, B2, a_, 0, 0, 0);   \
        a_ = __builtin_amdgcn_mfma_f32_16x16x32_bf16(ahi1, B3, a_, 0, 0, 0);   \
        a_ = __builtin_amdgcn_mfma_f32_16x16x32_bf16(alo0, B0, a_, 0, 0, 0);   \
        a_ = __builtin_amdgcn_mfma_f32_16x16x32_bf16(alo1, B1, a_, 0, 0, 0);   \
        _Pragma("unroll")                                                      \
        for (int r = 0; r < 4; ++r) {                                          \
            float v_ = a_[r];                                                  \
            bool c1_ = v_ > b1[r];                                             \
            bool c2_ = v_ > b2[r];                                             \
            b2[r] = __builtin_amdgcn_fmed3f(b1[r], v_, b2[r]);                 \
            b1[r] = fmaxf(b1[r], v_);                                          \
            i2[r] = c1_ ? i1[r] : (c2_ ? kc_ : i2[r]);                         \
            i1[r] = c1_ ? kc_ : i1[r];                                         \
        }                                                                      \
    } while (0)

    for (int t = 0; t < 64; t += 2) {
        COMPUTE(c0, c1, c2, c3, t);
        if (t + 2 < 64) LDB(c0, c1, c2, c3, t + 2);
        COMPUTE(n0, n1, n2, n3, t + 1);
        if (t + 3 < 64) LDB(n0, n1, n2, n3, t + 3);
    }

    // ---- merge per-lane top-2 across the 16 lanes per (wave,quad,reg) ----
    // store true dists (= -2*acc'); skew +4*(tx>>4) keeps reads ~2-way.
    const int sk = 4 * (tx + (tx >> 4));
#pragma unroll
    for (int r = 0; r < 4; ++r) {
        mb1[sk + r] = -2.f * b1[r];
        mb2[sk + r] = -2.f * b2[r];
        mi1[sk + r] = i1[r];
        mi2[sk + r] = i2[r];
    }
    __syncthreads();

    if (tx < 64) {   // thread tx owns local sample tx
        const int mw = tx >> 4, mq = (tx >> 2) & 3, mr = tx & 3;
        float B1 = 3.4e38f, B2 = 3.4e38f; int I1 = 0, I2 = 0;
#pragma unroll
        for (int c = 0; c < 16; ++c) {
            const int tw = mw * 64 + mq * 16 + c;
            const int e = 4 * (tw + (tw >> 4)) + mr;
            float v1 = mb1[e]; int j1 = mi1[e];
            float v2 = mb2[e]; int j2 = mi2[e];
            if (v1 < B1)      { B2 = B1; I2 = I1; B1 = v1; I1 = j1; }
            else if (v1 < B2) { B2 = v1; I2 = j1; }
            if (v2 < B1)      { B2 = B1; I2 = I1; B1 = v2; I1 = j2; }
            else if (v2 < B2) { B2 = v2; I2 = j2; }
        }
        int winner = I1;
        if (B2 - B1 < MARGIN) {
            // exact fp32 rescore of both candidates from original cm
            const float* xp = xin + (size_t)(S0 + tx) * D;
            float a0 = 0, a1 = 0, a2 = 0, a3 = 0, e0 = 0, e1 = 0, e2 = 0, e3 = 0;
            for (int dd = 0; dd < D; dd += 4) {
                float x0 = xp[dd], x1 = xp[dd + 1], x2 = xp[dd + 2], x3 = xp[dd + 3];
                a0 = fmaf(x0, cm[(dd + 0) * K + I1], a0);
                a1 = fmaf(x1, cm[(dd + 1) * K + I1], a1);
                a2 = fmaf(x2, cm[(dd + 2) * K + I1], a2);
                a3 = fmaf(x3, cm[(dd + 3) * K + I1], a3);
                e0 = fmaf(x0, cm[(dd + 0) * K + I2], e0);
                e1 = fmaf(x1, cm[(dd + 1) * K + I2], e1);
                e2 = fmaf(x2, cm[(dd + 2) * K + I2], e2);
                e3 = fmaf(x3, cm[(dd + 3) * K + I2], e3);
            }
            float d1 = fmaf(-2.f, (a0 + a1) + (a2 + a3), cn_lds[I1]);
            float d2 = fmaf(-2.f, (e0 + e1) + (e2 + e3), cn_lds[I2]);
            if (d2 < d1 || (d2 == d1 && I2 < I1)) winner = I2;
        }
        widx[tx] = winner;
    }
    __syncthreads();

    // ---- gather (hi+lo reconstruct from packed P) + STE + loss partial ----
    const int sl = tx >> 2, d0 = (tx & 3) * 16;
    const int gs = S0 + sl;
    const int wi = widx[sl];
    const int gt = wi >> 4, gc = wi & 15;
    const int qq = (d0 >> 3) & 3;        // 0 or 2
    const int gf = d0 >> 5;              // 0 or 1
    const unsigned short* gh = P + ((size_t)((gt * 4 + gf) * 64) + qq * 16 + gc) * 8;
    const unsigned short* gl = P + ((size_t)((gt * 4 + 2 + gf) * 64) + qq * 16 + gc) * 8;
    bf16x8 h0 = *(const bf16x8*)(gh);          // dims d0..d0+8
    bf16x8 h1 = *(const bf16x8*)(gh + 128);    // dims d0+8..d0+16
    bf16x8 l0 = *(const bf16x8*)(gl);
    bf16x8 l1 = *(const bf16x8*)(gl + 128);
    const float* xr = xin + (size_t)gs * D + d0;
    float* oq = outq + (size_t)gs * D + d0;
    float psum = 0.f;
#pragma unroll
    for (int g = 0; g < 4; ++g) {
        float4 xv = *(const float4*)(xr + 4 * g);
        float q0 = bf16f((unsigned short)(g < 2 ? h0[4 * g + 0] : h1[4 * g - 8 + 0])) +
                   bf16f((unsigned short)(g < 2 ? l0[4 * g + 0] : l1[4 * g - 8 + 0]));
        float q1 = bf16f((unsigned short)(g < 2 ? h0[4 * g + 1] : h1[4 * g - 8 + 1])) +
                   bf16f((unsigned short)(g < 2 ? l0[4 * g + 1] : l1[4 * g - 8 + 1]));
        float q2 = bf16f((unsigned short)(g < 2 ? h0[4 * g + 2] : h1[4 * g - 8 + 2])) +
                   bf16f((unsigned short)(g < 2 ? l0[4 * g + 2] : l1[4 * g - 8 + 2]));
        float q3 = bf16f((unsigned short)(g < 2 ? h0[4 * g + 3] : h1[4 * g - 8 + 3])) +
                   bf16f((unsigned short)(g < 2 ? l0[4 * g + 3] : l1[4 * g - 8 + 3]));
        float dx = q0 - xv.x, dy = q1 - xv.y, dz = q2 - xv.z, dw = q3 - xv.w;
        float4 o;
        o.x = xv.x + dx; o.y = xv.y + dy; o.z = xv.z + dz; o.w = xv.w + dw;
        *(float4*)(oq + 4 * g) = o;
        psum = fmaf(dx, dx, psum);
        psum = fmaf(dy, dy, psum);
        psum = fmaf(dz, dz, psum);
        psum = fmaf(dw, dw, psum);
    }

    if (tx < 64)
        outidx[S0 + tx] = (float)widx[tx];

    red[tx] = psum;
    __syncthreads();
    for (int st = 128; st > 0; st >>= 1) {
        if (tx < st) red[tx] += red[tx + st];
        __syncthreads();
    }
    if (tx == 0) atomicAdd(acc_g, (double)red[0]);
#undef LDB
#undef COMPUTE
}

// ---------------------------------------------------------------------------
// Finalize: loss = m + 0.25*m where m = mean((q-x)^2)
// ---------------------------------------------------------------------------
__global__ void vq_finalize(const double* __restrict__ acc,
                            float* __restrict__ loss_out)
{
    float m = (float)(*acc / (double)NEL);
    *loss_out = m + 0.25f * m;
}

extern "C" void kernel_launch(void* const* d_in, const int* in_sizes, int n_in,
                              void* d_out, int out_size, void* d_ws, size_t ws_size,
                              hipStream_t stream) {
    const float* xin = (const float*)d_in[0];   // [16,64,64,64] fp32
    const float* cm  = (const float*)d_in[1];   // [64,1024] fp32

    float* out     = (float*)d_out;
    float* outq    = out;                 // 4194304 floats
    float* outidx  = out + NEL;           // 65536 floats (indices)
    float* outloss = out + NEL + NS;      // 1 float

    // workspace: packed P 256 KB | cnorm 4 KB | acc 8 B
    unsigned short* P = (unsigned short*)d_ws;
    float*  cnorm = (float*)((char*)d_ws + 262144);
    double* acc   = (double*)((char*)d_ws + 266240);

    vq_prep<<<64, 256, 0, stream>>>(cm, P, cnorm, acc);
    vq_main<<<1024, 256, 0, stream>>>(xin, cm, P, cnorm, outq, outidx, acc);
    vq_finalize<<<1, 1, 0, stream>>>(acc, outloss);
}